// Round 2
// baseline (16625.371 us; speedup 1.0000x reference)
//
#include <hip/hip_runtime.h>
#include <hip/hip_fp16.h>

#define NB 128
#define ND 1280
#define NK 49
#define NV 10000
#define NT 40
#define N4D 5120

typedef unsigned long long u64;

// ---------------- fp32 GEMM core: M=128 fixed, N-tile=64, K-chunk via split-K ----
// C[m, n0+j] = sum_{k in [kbase,kbase+kc)} A[m,k] * B[k,n]
// A: rows m, cols k; source split at asplit (A0 below, A1 above).
// B: rows k, cols n; source split at bsplit.
__device__ __forceinline__ void gemm_core(
    const float* __restrict__ A0, const float* __restrict__ A1, int asplit, int lda,
    const float* __restrict__ B0, const float* __restrict__ B1, int bsplit, int ldb,
    int n0, int N, int kbase, int kc, float* __restrict__ C)
{
  __shared__ float Al[2][16][132];
  __shared__ float Bl[2][16][68];
  const int tid = threadIdx.x;
  const int tn = tid & 15, tm = tid >> 4;
  float acc[8][4];
#pragma unroll
  for (int i = 0; i < 8; ++i)
#pragma unroll
    for (int j = 0; j < 4; ++j) acc[i][j] = 0.f;

  const int am  = tid >> 1;           // A row handled by this thread
  const int ac0 = (tid & 1) * 8;      // A col base (0 or 8)
  const int br  = tid >> 4;           // B row
  const int bc  = (tid & 15) * 4;     // B col within tile
  const int bcol = n0 + bc;
  const int ntile = kc >> 4;

  float4 ra0, ra1, rb;

  auto load_tile = [&](int t) {
    const int kg = kbase + (t << 4);
    const float* Ab = (kg < asplit) ? (A0 + kg) : (A1 + (kg - asplit));
    const float* Bb = (kg < bsplit) ? (B0 + (size_t)kg * ldb)
                                    : (B1 + (size_t)(kg - bsplit) * ldb);
    ra0 = *(const float4*)(Ab + (size_t)am * lda + ac0);
    ra1 = *(const float4*)(Ab + (size_t)am * lda + ac0 + 4);
    if (bcol < N) rb = *(const float4*)(Bb + (size_t)br * ldb + bcol);
    else rb = make_float4(0.f, 0.f, 0.f, 0.f);
  };
  auto store_tile = [&](int buf) {
    Al[buf][ac0 + 0][am] = ra0.x; Al[buf][ac0 + 1][am] = ra0.y;
    Al[buf][ac0 + 2][am] = ra0.z; Al[buf][ac0 + 3][am] = ra0.w;
    Al[buf][ac0 + 4][am] = ra1.x; Al[buf][ac0 + 5][am] = ra1.y;
    Al[buf][ac0 + 6][am] = ra1.z; Al[buf][ac0 + 7][am] = ra1.w;
    *(float4*)&Bl[buf][br][bc] = rb;
  };

  load_tile(0); store_tile(0); __syncthreads();
  for (int t = 0; t < ntile; ++t) {
    if (t + 1 < ntile) load_tile(t + 1);
    const int buf = t & 1;
#pragma unroll
    for (int kk = 0; kk < 16; ++kk) {
      const float4 a0 = *(const float4*)&Al[buf][kk][tm * 8];
      const float4 a1 = *(const float4*)&Al[buf][kk][tm * 8 + 4];
      const float4 b4 = *(const float4*)&Bl[buf][kk][tn * 4];
      const float amv[8] = {a0.x, a0.y, a0.z, a0.w, a1.x, a1.y, a1.z, a1.w};
      const float bvv[4] = {b4.x, b4.y, b4.z, b4.w};
#pragma unroll
      for (int i = 0; i < 8; ++i)
#pragma unroll
        for (int j = 0; j < 4; ++j)
          acc[i][j] = fmaf(amv[i], bvv[j], acc[i][j]);
    }
    __syncthreads();
    if (t + 1 < ntile) { store_tile((t + 1) & 1); __syncthreads(); }
  }
  const int ccol = n0 + tn * 4;
  if (ccol < N) {
#pragma unroll
    for (int i = 0; i < 8; ++i) {
      float4 v = make_float4(acc[i][0], acc[i][1], acc[i][2], acc[i][3]);
      *(float4*)(C + (size_t)(tm * 8 + i) * N + ccol) = v;
    }
  }
}

// ---- GEMM wrappers ----
// gates: [x|h](128x2560) @ [Wih;Whh](2560x5120), split-K S=8 (KC=320)
__global__ __launch_bounds__(256) void k_gates(const float* __restrict__ x,
    const float* __restrict__ h, const float* __restrict__ Wih,
    const float* __restrict__ Whh, float* __restrict__ part)
{
  int n0 = blockIdx.x * 64, s = blockIdx.y;
  gemm_core(x, h, ND, ND, Wih, Whh, ND, N4D, n0, N4D, s * 320, 320,
            part + (size_t)s * NB * N4D);
}
// logits: h_new(128x1280) @ Wp(1280x10000), split-K S=4
__global__ __launch_bounds__(256) void k_logits(const float* __restrict__ hn,
    const float* __restrict__ Wp, float* __restrict__ part)
{
  int n0 = blockIdx.x * 64, s = blockIdx.y;
  gemm_core(hn, hn, 1 << 28, ND, Wp, Wp, 1 << 28, NV, n0, NV, s * 320, 320,
            part + (size_t)s * NB * NV);
}
// q: [h_new;c_new](256x1280) @ Wq(1280x1280), split-K S=4, z selects source half
__global__ __launch_bounds__(256) void k_qgemm(const float* __restrict__ hn,
    const float* __restrict__ cn, const float* __restrict__ Wq, float* __restrict__ part)
{
  int n0 = blockIdx.x * 64, s = blockIdx.y, z = blockIdx.z;
  const float* A = z ? cn : hn;
  gemm_core(A, A, 1 << 28, ND, Wq, Wq, 1 << 28, ND, n0, ND, s * 320, 320,
            part + (size_t)s * 256 * ND + (size_t)z * NB * ND);
}
// gating: [att_z|state_z](128x2560) @ (Wh or Wc)(2560x1280), split-K S=8
__global__ __launch_bounds__(256) void k_ggemm(const float* __restrict__ att,
    const float* __restrict__ hn, const float* __restrict__ cn,
    const float* __restrict__ Wh, const float* __restrict__ Wc, float* __restrict__ part)
{
  int n0 = blockIdx.x * 64, s = blockIdx.y, z = blockIdx.z;
  const float* A0 = att + (size_t)z * NB * ND;
  const float* A1 = z ? cn : hn;
  const float* Bw = z ? Wc : Wh;
  gemm_core(A0, A1, ND, ND, Bw, Bw, 1 << 28, ND, n0, ND, s * 320, 320,
            part + (size_t)z * 8 * NB * ND + (size_t)s * NB * ND);
}

// ---- LSTM pointwise: reduce 8 gate partials, apply cell; also clears argmax ws ----
__global__ __launch_bounds__(256) void k_lstm(const float* __restrict__ part,
    const float* __restrict__ bih, const float* __restrict__ bhh,
    const float* __restrict__ c_st, float* __restrict__ hn, float* __restrict__ cn,
    u64* __restrict__ amax)
{
  int idx = blockIdx.x * 256 + threadIdx.x;   // < 163840 exactly
  if (idx < NB) amax[idx] = 0ULL;
  int b = idx / ND, d = idx % ND;
  const float* gp = part + (size_t)b * N4D;
  float gi = bih[d]          + bhh[d];
  float gf = bih[ND + d]     + bhh[ND + d];
  float gg = bih[2 * ND + d] + bhh[2 * ND + d];
  float go = bih[3 * ND + d] + bhh[3 * ND + d];
#pragma unroll
  for (int s = 0; s < 8; ++s) {
    const float* p = gp + (size_t)s * NB * N4D;
    gi += p[d]; gf += p[ND + d]; gg += p[2 * ND + d]; go += p[3 * ND + d];
  }
  float c = c_st[idx];
  float si = 1.f / (1.f + expf(-gi));
  float sf = 1.f / (1.f + expf(-gf));
  float so = 1.f / (1.f + expf(-go));
  float cnew = sf * c + si * tanhf(gg);
  float hnew = so * tanhf(cnew);
  cn[idx] = cnew; hn[idx] = hnew;
}

// ---- logits reduce: sum split-K partials + bias, stage fp16 slice, argmax ----
__device__ __forceinline__ u64 pack_max(float v, int n) {
  unsigned u = __float_as_uint(v);
  u = (u & 0x80000000u) ? ~u : (u | 0x80000000u);   // monotonic encode
  return ((u64)u << 32) | (u64)(0xFFFFFFFFu - (unsigned)n);  // ties -> smaller n
}
__global__ __launch_bounds__(256) void k_lred(const float* __restrict__ part,
    const float* __restrict__ bp, __half* __restrict__ stage, float* __restrict__ outp,
    int tslice, int staged, u64* __restrict__ amax)
{
  int b = blockIdx.y;
  int nbeg = blockIdx.x * 2000, nend = nbeg + 2000;
  u64 best = 0ULL;
  for (int n = nbeg + (int)threadIdx.x; n < nend; n += 256) {
    float v = bp[n];
#pragma unroll
    for (int s = 0; s < 4; ++s) v += part[(size_t)s * NB * NV + (size_t)b * NV + n];
    if (staged) stage[(size_t)tslice * NB * NV + (size_t)b * NV + n] = __float2half(v);
    else outp[((size_t)b * NV + n) * NT + tslice] = v;
    u64 p = pack_max(v, n);
    best = best > p ? best : p;
  }
  __shared__ u64 red[256];
  red[threadIdx.x] = best; __syncthreads();
  for (int off = 128; off > 0; off >>= 1) {
    if ((int)threadIdx.x < off) {
      u64 o = red[threadIdx.x + off];
      if (o > red[threadIdx.x]) red[threadIdx.x] = o;
    }
    __syncthreads();
  }
  if (threadIdx.x == 0) atomicMax(amax + b, red[0]);
}

// ---- attention: q reduce+tanh, scores via kmatT, softmax, weighted V; + x gather ----
__global__ __launch_bounds__(256) void k_attn(const float* __restrict__ qpart,
    const float* __restrict__ bq, const float* __restrict__ kmatT,
    const float* __restrict__ vmat, float* __restrict__ att,
    const u64* __restrict__ amax, const float* __restrict__ embed,
    float* __restrict__ x_st)
{
  int bb = blockIdx.x;
  if (bb >= NB) {                 // 2 trailing blocks: x_next = embed[argmax]
    int half = bb - NB;
    for (int idx = half * 81920 + (int)threadIdx.x; idx < (half + 1) * 81920; idx += 256) {
      int b = idx / ND, d = idx % ND;
      int n = (int)(0xFFFFFFFFu - (unsigned)(amax[b] & 0xFFFFFFFFULL));
      x_st[idx] = embed[(size_t)n * ND + d];
    }
    return;
  }
  __shared__ float qh[ND], qc[ND];
  __shared__ float sc[2][64];
  __shared__ float wl[2][64];
  int tid = threadIdx.x;
  for (int d = tid; d < ND; d += 256) {
    float ah = bq[d], ac = bq[d];
#pragma unroll
    for (int s = 0; s < 4; ++s) {
      ah += qpart[(size_t)s * 256 * ND + (size_t)bb * ND + d];
      ac += qpart[(size_t)s * 256 * ND + (size_t)(NB + bb) * ND + d];
    }
    qh[d] = tanhf(ah); qc[d] = tanhf(ac);
  }
  __syncthreads();
  int w = tid >> 6, lane = tid & 63;
  for (int kk = w; kk < NK; kk += 4) {
    const float4* kr = (const float4*)(kmatT + ((size_t)bb * NK + kk) * ND);
    float ah = 0.f, ac = 0.f;
#pragma unroll
    for (int c = 0; c < 5; ++c) {
      float4 kv = kr[c * 64 + lane];
      const float4 q4h = *(const float4*)&qh[(c * 64 + lane) * 4];
      const float4 q4c = *(const float4*)&qc[(c * 64 + lane) * 4];
      ah += kv.x * q4h.x + kv.y * q4h.y + kv.z * q4h.z + kv.w * q4h.w;
      ac += kv.x * q4c.x + kv.y * q4c.y + kv.z * q4c.z + kv.w * q4c.w;
    }
#pragma unroll
    for (int off = 32; off > 0; off >>= 1) {
      ah += __shfl_down(ah, off);
      ac += __shfl_down(ac, off);
    }
    if (lane == 0) { sc[0][kk] = ah / 7.0f; sc[1][kk] = ac / 7.0f; }
  }
  __syncthreads();
  if (w < 2) {
    float s = (lane < NK) ? sc[w][lane] : -3.4e38f;
    float mx = s;
#pragma unroll
    for (int off = 32; off > 0; off >>= 1) mx = fmaxf(mx, __shfl_xor(mx, off));
    float e = (lane < NK) ? expf(s - mx) : 0.f;
    float sum = e;
#pragma unroll
    for (int off = 32; off > 0; off >>= 1) sum += __shfl_xor(sum, off);
    wl[w][lane] = (lane < NK) ? e / sum : 0.f;
  }
  __syncthreads();
  for (int d = tid; d < ND; d += 256) {
    const float4* vr = (const float4*)(vmat + ((size_t)bb * ND + d) * 52);
    float ah = 0.f, ac = 0.f;
#pragma unroll
    for (int c4 = 0; c4 < 13; ++c4) {
      float4 v = vr[c4];
      ah += wl[0][c4 * 4 + 0] * v.x + wl[0][c4 * 4 + 1] * v.y
          + wl[0][c4 * 4 + 2] * v.z + wl[0][c4 * 4 + 3] * v.w;
      ac += wl[1][c4 * 4 + 0] * v.x + wl[1][c4 * 4 + 1] * v.y
          + wl[1][c4 * 4 + 2] * v.z + wl[1][c4 * 4 + 3] * v.w;
    }
    att[(size_t)bb * ND + d] = ah;
    att[(size_t)(NB + bb) * ND + d] = ac;
  }
}

// ---- gating reduce: tanh(sum partials + bias) -> new h/c state ----
__global__ __launch_bounds__(256) void k_gred(const float* __restrict__ part,
    const float* __restrict__ bh, const float* __restrict__ bc,
    float* __restrict__ h_st, float* __restrict__ c_st)
{
  int idx = blockIdx.x * 256 + threadIdx.x;   // < 327680 exactly
  int z = idx / (NB * ND); int rem = idx - z * NB * ND; int d = rem % ND;
  float v = z ? bc[d] : bh[d];
  const float* p = part + (size_t)z * 8 * NB * ND + rem;
#pragma unroll
  for (int s = 0; s < 8; ++s) v += p[(size_t)s * NB * ND];
  v = tanhf(v);
  if (z) c_st[rem] = v; else h_st[rem] = v;
}

// ---- init: h=c=pooled, x=embed[SOS=0] ----
__global__ __launch_bounds__(256) void k_init(const float* __restrict__ pooled,
    const float* __restrict__ embed, float* __restrict__ h, float* __restrict__ c,
    float* __restrict__ x)
{
  int idx = blockIdx.x * 256 + threadIdx.x;   // < 163840 exactly
  float p = pooled[idx];
  h[idx] = p; c[idx] = p;
  x[idx] = embed[idx % ND];
}

// ---- precompute kmatT[b][k][d] = tanh(ch@Wk+bk)^T, vmat[b][d][0..51] (padded) ----
__global__ __launch_bounds__(256) void k_kv(const float* __restrict__ ch,
    const float* __restrict__ Wk, const float* __restrict__ bk,
    const float* __restrict__ Wv, const float* __restrict__ bv,
    float* __restrict__ kmatT, float* __restrict__ vmat)
{
  __shared__ float sbuf[256 * NK];           // ch chunk, later reused as k-transpose
  __shared__ float Wkl[NK * NK], Wvl[NK * NK], bkl[64], bvl[64];
  int b = blockIdx.y, d0 = blockIdx.x * 256, tid = threadIdx.x;
  for (int i = tid; i < NK * NK; i += 256) { Wkl[i] = Wk[i]; Wvl[i] = Wv[i]; }
  if (tid < NK) { bkl[tid] = bk[tid]; bvl[tid] = bv[tid]; }
  const size_t chbase = ((size_t)b * ND + d0) * NK;
  for (int i = tid; i < 256 * NK; i += 256) sbuf[i] = ch[chbase + i];
  __syncthreads();
  float rr[NK];
#pragma unroll
  for (int k = 0; k < NK; ++k) rr[k] = sbuf[tid * NK + k];
  // v pass (direct global writes, row padded to 52 with zeros)
  size_t vb = ((size_t)b * ND + d0 + tid) * 52;
  for (int j = 0; j < NK; ++j) {
    float a = bvl[j];
#pragma unroll
    for (int k = 0; k < NK; ++k) a = fmaf(rr[k], Wvl[k * NK + j], a);
    vmat[vb + j] = tanhf(a);
  }
  vmat[vb + 49] = 0.f; vmat[vb + 50] = 0.f; vmat[vb + 51] = 0.f;
  __syncthreads();                            // everyone done reading sbuf(ch)
  // k pass: write transposed into sbuf
  for (int j = 0; j < NK; ++j) {
    float a = bkl[j];
#pragma unroll
    for (int k = 0; k < NK; ++k) a = fmaf(rr[k], Wkl[k * NK + j], a);
    sbuf[j * 256 + tid] = tanhf(a);
  }
  __syncthreads();
  for (int i = tid; i < NK * 256; i += 256) {
    int j = i >> 8, dd = i & 255;
    kmatT[((size_t)b * NK + j) * ND + d0 + dd] = sbuf[i];
  }
}

// ---- t=0 logits: embed[SOS]@Wp + bp, identical for all b ----
__global__ __launch_bounds__(256) void k_l0(const float* __restrict__ embed,
    const float* __restrict__ Wp, const float* __restrict__ bp,
    __half* __restrict__ stage, float* __restrict__ outp, int staged)
{
  __shared__ float e0[ND];
  int tid = threadIdx.x;
  for (int i = tid; i < ND; i += 256) e0[i] = embed[i];
  __syncthreads();
  int n = blockIdx.x * 256 + tid;
  if (n >= NV) return;
  float a = bp[n];
  for (int d = 0; d < ND; ++d) a = fmaf(e0[d], Wp[(size_t)d * NV + n], a);
  if (staged) {
    for (int b = 0; b < NB; ++b) stage[(size_t)b * NV + n] = __float2half(a);
  } else {
    for (int b = 0; b < NB; ++b) outp[((size_t)b * NV + n) * NT] = a;
  }
}

// ---- final transpose: stage[t][b][n] (fp16) -> out[b][n][t] (fp32) ----
__global__ __launch_bounds__(256) void k_tr(const __half* __restrict__ stage,
    float* __restrict__ outp)
{
  __shared__ float tl[64][41];
  int b = blockIdx.y, n0 = blockIdx.x * 64, tid = threadIdx.x;
  for (int i = tid; i < 2560; i += 256) {
    int t = i >> 6, n = i & 63;
    float v = (n0 + n < NV)
        ? __half2float(stage[(size_t)t * NB * NV + (size_t)b * NV + n0 + n]) : 0.f;
    tl[n][t] = v;
  }
  __syncthreads();
  for (int i = tid; i < 640; i += 256) {
    int row = i / 10, c4 = i % 10;
    if (n0 + row < NV) {
      float4 v = make_float4(tl[row][c4 * 4], tl[row][c4 * 4 + 1],
                             tl[row][c4 * 4 + 2], tl[row][c4 * 4 + 3]);
      *(float4*)(outp + ((size_t)b * NV + n0 + row) * NT + c4 * 4) = v;
    }
  }
}

extern "C" void kernel_launch(void* const* d_in, const int* in_sizes, int n_in,
                              void* d_out, int out_size, void* d_ws, size_t ws_size,
                              hipStream_t stream) {
  const float* ch     = (const float*)d_in[0];
  const float* pooled = (const float*)d_in[1];
  const float* Wih    = (const float*)d_in[2];
  const float* Whh    = (const float*)d_in[3];
  const float* bih    = (const float*)d_in[4];
  const float* bhh    = (const float*)d_in[5];
  const float* Wq     = (const float*)d_in[6];
  const float* bq     = (const float*)d_in[7];
  const float* Wk     = (const float*)d_in[8];
  const float* bk     = (const float*)d_in[9];
  const float* Wv     = (const float*)d_in[10];
  const float* bv     = (const float*)d_in[11];
  const float* Wh     = (const float*)d_in[12];
  const float* bh     = (const float*)d_in[13];
  const float* Wc     = (const float*)d_in[14];
  const float* bc     = (const float*)d_in[15];
  const float* Wp     = (const float*)d_in[16];
  const float* bp     = (const float*)d_in[17];
  const float* embed  = (const float*)d_in[18];
  float* outp = (float*)d_out;

  char* w = (char*)d_ws;
  size_t off = 0;
  auto alloc = [&](size_t bytes) {
    void* p = w + off; off += (bytes + 255) & ~(size_t)255; return p;
  };
  float* kmatT  = (float*)alloc((size_t)NB * NK * ND * 4);
  float* vmat   = (float*)alloc((size_t)NB * ND * 52 * 4);
  float* h_st   = (float*)alloc((size_t)NB * ND * 4);
  float* c_st   = (float*)alloc((size_t)NB * ND * 4);
  float* x_st   = (float*)alloc((size_t)NB * ND * 4);
  float* h_new  = (float*)alloc((size_t)NB * ND * 4);
  float* c_new  = (float*)alloc((size_t)NB * ND * 4);
  float* gpart  = (float*)alloc((size_t)8 * NB * N4D * 4);
  float* lpart  = (float*)alloc((size_t)4 * NB * NV * 4);
  float* qpart  = (float*)alloc((size_t)4 * 256 * ND * 4);
  float* attb   = (float*)alloc((size_t)256 * ND * 4);
  float* g2part = (float*)alloc((size_t)2 * 8 * NB * ND * 4);
  u64*   amax   = (u64*)alloc((size_t)NB * 8);
  __half* stage = (__half*)alloc((size_t)NT * NB * NV * 2);
  int staged = (ws_size >= off) ? 1 : 0;   // fallback: strided direct writes

  k_init<<<640, 256, 0, stream>>>(pooled, embed, h_st, c_st, x_st);
  k_kv<<<dim3(5, NB), 256, 0, stream>>>(ch, Wk, bk, Wv, bv, kmatT, vmat);
  k_l0<<<40, 256, 0, stream>>>(embed, Wp, bp, stage, outp, staged);

  for (int s = 0; s < NT - 1; ++s) {
    k_gates<<<dim3(80, 8), 256, 0, stream>>>(x_st, h_st, Wih, Whh, gpart);
    k_lstm<<<640, 256, 0, stream>>>(gpart, bih, bhh, c_st, h_new, c_new, amax);
    k_logits<<<dim3(157, 4), 256, 0, stream>>>(h_new, Wp, lpart);
    k_lred<<<dim3(5, NB), 256, 0, stream>>>(lpart, bp, stage, outp, s + 1, staged, amax);
    k_qgemm<<<dim3(20, 4, 2), 256, 0, stream>>>(h_new, c_new, Wq, qpart);
    k_attn<<<130, 256, 0, stream>>>(qpart, bq, kmatT, vmat, attb, amax, embed, x_st);
    k_ggemm<<<dim3(20, 8, 2), 256, 0, stream>>>(attb, h_new, c_new, Wh, Wc, g2part);
    k_gred<<<1280, 256, 0, stream>>>(g2part, bh, bc, h_st, c_st);
  }
  if (staged) k_tr<<<dim3(157, NB), 256, 0, stream>>>(stage, outp);
}